// Round 2
// baseline (190968.433 us; speedup 1.0000x reference)
//
#include <hip/hip_runtime.h>
#include <cstddef>
#include <cstdint>

#define NB 32     // batch
#define HD 512    // hidden
#define GD 2048   // 4*hidden

__device__ __forceinline__ float sigf(float x)   { return 1.0f / (1.0f + __expf(-x)); }
__device__ __forceinline__ float tanhf_(float x) { return 2.0f / (1.0f + __expf(-2.0f * x)) - 1.0f; }

#define FMA16_BLOCK \
    acc[0][0] = fmaf(a4.x, b4.x, acc[0][0]); \
    acc[0][1] = fmaf(a4.x, b4.y, acc[0][1]); \
    acc[0][2] = fmaf(a4.x, b4.z, acc[0][2]); \
    acc[0][3] = fmaf(a4.x, b4.w, acc[0][3]); \
    acc[1][0] = fmaf(a4.y, b4.x, acc[1][0]); \
    acc[1][1] = fmaf(a4.y, b4.y, acc[1][1]); \
    acc[1][2] = fmaf(a4.y, b4.z, acc[1][2]); \
    acc[1][3] = fmaf(a4.y, b4.w, acc[1][3]); \
    acc[2][0] = fmaf(a4.z, b4.x, acc[2][0]); \
    acc[2][1] = fmaf(a4.z, b4.y, acc[2][1]); \
    acc[2][2] = fmaf(a4.z, b4.z, acc[2][2]); \
    acc[2][3] = fmaf(a4.z, b4.w, acc[2][3]); \
    acc[3][0] = fmaf(a4.w, b4.x, acc[3][0]); \
    acc[3][1] = fmaf(a4.w, b4.y, acc[3][1]); \
    acc[3][2] = fmaf(a4.w, b4.z, acc[3][2]); \
    acc[3][3] = fmaf(a4.w, b4.w, acc[3][3]);

// xg[b][tc][n] = sum_k A[b, t0+tc, k] * Wih[n, k] + bih[n] + bhh[n]
__global__ __launch_bounds__(256) void gemm_xg(
    const float* __restrict__ A, int T, int t0, int tc_bits,
    const float* __restrict__ W,
    const float* __restrict__ bih, const float* __restrict__ bhh,
    float* __restrict__ out)
{
    __shared__ __align__(16) float As[16][68];
    __shared__ __align__(16) float Bs[16][68];
    const int tid = threadIdx.x;
    const int tx = tid & 15, ty = tid >> 4;
    const int m0 = blockIdx.x << 6, n0 = blockIdx.y << 6;
    const int lr = tid >> 2;
    const int lk = (tid & 3) << 2;
    const int r  = m0 + lr;
    const int b  = r >> tc_bits;
    const int tt = t0 + (r & ((1 << tc_bits) - 1));
    const float* aRow = A + (((size_t)b * T + tt) << 9) + lk;
    const float* wRow = W + (((size_t)(n0 + lr)) << 9) + lk;
    float acc[4][4] = {};
    for (int k0 = 0; k0 < HD; k0 += 16) {
        const float4 av = *(const float4*)(aRow + k0);
        const float4 wv = *(const float4*)(wRow + k0);
        As[lk][lr] = av.x; As[lk + 1][lr] = av.y; As[lk + 2][lr] = av.z; As[lk + 3][lr] = av.w;
        Bs[lk][lr] = wv.x; Bs[lk + 1][lr] = wv.y; Bs[lk + 2][lr] = wv.z; Bs[lk + 3][lr] = wv.w;
        __syncthreads();
#pragma unroll
        for (int k = 0; k < 16; ++k) {
            const float4 a4 = *(const float4*)&As[k][ty << 2];
            const float4 b4 = *(const float4*)&Bs[k][tx << 2];
            FMA16_BLOCK
        }
        __syncthreads();
    }
#pragma unroll
    for (int i = 0; i < 4; ++i) {
        const int rr = m0 + (ty << 2) + i;
#pragma unroll
        for (int j = 0; j < 4; ++j) {
            const int nn = n0 + (tx << 2) + j;
            out[((size_t)rr << 11) + nn] = acc[i][j] + bih[nn] + bhh[nn];
        }
    }
}

// Upsample + residual add into next tier input
__global__ __launch_bounds__(256) void gemm_up(
    const float* __restrict__ A,
    const float* __restrict__ W, int N,
    const float* __restrict__ bias,
    const float* __restrict__ xnext,
    float* __restrict__ dst, int t_bits, int u_bits)
{
    __shared__ __align__(16) float As[16][68];
    __shared__ __align__(16) float Bs[16][68];
    const int tid = threadIdx.x;
    const int tx = tid & 15, ty = tid >> 4;
    const int m0 = blockIdx.x << 6, n0 = blockIdx.y << 6;
    const int lr = tid >> 2, lk = (tid & 3) << 2;
    const float* aRow = A + (((size_t)(m0 + lr)) << 9) + lk;
    const int wk = tid >> 4, wn = (tid & 15) << 2;
    float acc[4][4] = {};
    for (int k0 = 0; k0 < HD; k0 += 16) {
        const float4 av = *(const float4*)(aRow + k0);
        const float4 wv = *(const float4*)(W + (size_t)(k0 + wk) * N + n0 + wn);
        As[lk][lr] = av.x; As[lk + 1][lr] = av.y; As[lk + 2][lr] = av.z; As[lk + 3][lr] = av.w;
        *(float4*)&Bs[wk][wn] = wv;
        __syncthreads();
#pragma unroll
        for (int k = 0; k < 16; ++k) {
            const float4 a4 = *(const float4*)&As[k][ty << 2];
            const float4 b4 = *(const float4*)&Bs[k][tx << 2];
            FMA16_BLOCK
        }
        __syncthreads();
    }
    const int T_1 = (1 << t_bits) - 1;
#pragma unroll
    for (int i = 0; i < 4; ++i) {
        const int rr = m0 + (ty << 2) + i;
        const int bb = rr >> t_bits, tt = rr & T_1;
#pragma unroll
        for (int j = 0; j < 4; ++j) {
            const int nn = n0 + (tx << 2) + j;
            const int uu = nn >> 9, hh = nn & 511;
            const size_t di = (((size_t)((((bb << t_bits) + tt) << u_bits) + uu)) << 9) + hh;
            dst[di] = acc[i][j] + bias[nn] + xnext[di];
        }
    }
}

// Persistent scan: 256 blocks (1/CU), Tc steps per launch, one flag-barrier/step.
// Block bid owns hidden units {2bid, 2bid+1} for all 4 gates (8 Whh rows in LDS).
// Thread map: b8 = tid>>3 (batch), r_l = tid&7 (= gate*2 + jl).
__global__ __launch_bounds__(256, 1) void lstm_scan(
    const float* __restrict__ xg, int Tc,        // (NB, Tc, GD)
    const float* __restrict__ Whh,               // (GD, HD)
    const float* __restrict__ h0,                // (NB, HD) initial h (used when t==0)
    float* __restrict__ outh, int T, int t0,     // h series (NB, T, HD)
    float* __restrict__ cws,                     // (NB, HD) persistent c
    unsigned* __restrict__ flags)                // 256, zeroed before launch
{
    __shared__ __align__(16) float w_lds[8 * 516];
    __shared__ __align__(16) float hs[32 * 516];
    __shared__ float gl[32][9];
    __shared__ float c_lds[32][2];
    const int tid = threadIdx.x;
    const int bid = blockIdx.x;
    const int j0 = bid << 1;
    const int b8 = tid >> 3;          // 0..31
    const int r_l = tid & 7;          // gate*2 + jl
    const int grow = ((r_l >> 1) << 9) + j0 + (r_l & 1);

    // Load this block's 8 Whh rows into LDS (stride 516 for bank balance)
#pragma unroll
    for (int i = 0; i < 4; ++i) {
        const int f4i = tid + (i << 8);
        const int r = f4i >> 7, q = f4i & 127;
        const int rr = ((r >> 1) << 9) + j0 + (r & 1);
        const float4 v = *(const float4*)(Whh + (((size_t)rr) << 9) + (q << 2));
        *(float4*)(w_lds + r * 516 + (q << 2)) = v;
    }
    if (tid < 64) {
        const int b = tid >> 1, jj = tid & 1;
        c_lds[b][jj] = cws[(b << 9) + j0 + jj];
    }
    __syncthreads();

    const float4* wr4 = (const float4*)(w_lds + r_l * 516);
    const float4* hb4 = (const float4*)(hs + b8 * 516);

    for (int s = 0; s < Tc; ++s) {
        const int t = t0 + s;
        // prefetch this thread's xg value (independent of h)
        const float xgv = xg[(((size_t)b8 * Tc + s) << 11) + grow];
        // stage h_{t-1} into LDS, coalesced
        const float* hp; size_t hstr;
        if (t == 0) { hp = h0; hstr = 512; }
        else        { hp = outh + ((size_t)(t - 1) << 9); hstr = (size_t)T << 9; }
#pragma unroll
        for (int i = 0; i < 16; ++i) {
            const int f4i = tid + (i << 8);
            const int b = f4i >> 7, q = f4i & 127;
            const float4 v = *(const float4*)(hp + (size_t)b * hstr + (q << 2));
            *(float4*)(hs + b * 516 + (q << 2)) = v;
        }
        __syncthreads();
        // matvec: row r_l of block's Whh slice dot h[b8]
        float acc = 0.f;
#pragma unroll 8
        for (int k4 = 0; k4 < 128; ++k4) {
            const float4 h4 = hb4[k4];
            const float4 w4 = wr4[k4];
            acc = fmaf(w4.x, h4.x, acc); acc = fmaf(w4.y, h4.y, acc);
            acc = fmaf(w4.z, h4.z, acc); acc = fmaf(w4.w, h4.w, acc);
        }
        gl[b8][r_l] = acc + xgv;
        __syncthreads();
        if (tid < 64) {
            const int b = tid >> 1, jj = tid & 1;
            const float gi = gl[b][0 + jj], gf = gl[b][2 + jj];
            const float gg = gl[b][4 + jj], go = gl[b][6 + jj];
            const float c = sigf(gf) * c_lds[b][jj] + sigf(gi) * tanhf_(gg);
            c_lds[b][jj] = c;
            const float h = sigf(go) * tanhf_(c);
            __hip_atomic_store(outh + (((size_t)b * T + t) << 9) + j0 + jj, h,
                               __ATOMIC_RELAXED, __HIP_MEMORY_SCOPE_AGENT);
        }
        // device-wide barrier: release own flag, acquire all flags
        __threadfence();
        __syncthreads();
        if (tid == 0)
            __hip_atomic_store(flags + bid, (unsigned)(s + 1),
                               __ATOMIC_RELEASE, __HIP_MEMORY_SCOPE_AGENT);
        const unsigned tgt = (unsigned)(s + 1);
        while (__hip_atomic_load(flags + tid, __ATOMIC_ACQUIRE,
                                 __HIP_MEMORY_SCOPE_AGENT) < tgt) {
            __builtin_amdgcn_s_sleep(2);
        }
        __syncthreads();
    }
    if (tid < 64) {
        const int b = tid >> 1, jj = tid & 1;
        cws[(b << 9) + j0 + jj] = c_lds[b][jj];
    }
}

extern "C" void kernel_launch(void* const* d_in, const int* in_sizes, int n_in,
                              void* d_out, int out_size, void* d_ws, size_t ws_size,
                              hipStream_t stream)
{
    const float* x[3]   = {(const float*)d_in[0], (const float*)d_in[1],  (const float*)d_in[2]};
    const float* Wih[3] = {(const float*)d_in[3], (const float*)d_in[9],  (const float*)d_in[15]};
    const float* Whh[3] = {(const float*)d_in[4], (const float*)d_in[10], (const float*)d_in[16]};
    const float* bih[3] = {(const float*)d_in[5], (const float*)d_in[11], (const float*)d_in[17]};
    const float* bhh[3] = {(const float*)d_in[6], (const float*)d_in[12], (const float*)d_in[18]};
    const float* h0[3]  = {(const float*)d_in[7], (const float*)d_in[13], (const float*)d_in[19]};
    const float* c0[3]  = {(const float*)d_in[8], (const float*)d_in[14], (const float*)d_in[20]};
    const float* upW[2] = {(const float*)d_in[21], (const float*)d_in[23]};
    const float* upb[2] = {(const float*)d_in[22], (const float*)d_in[24]};

    float* ws = (float*)d_ws;
    float* bufA = ws;                               // 4M floats
    float* bufB = ws + (size_t)NB * 256 * HD;       // 4M floats
    const size_t fixed = 2 * (size_t)NB * 256 * HD + (size_t)NB * HD + 512;
    int Tc_cap = 256;
    while (Tc_cap > 32 && (fixed + (size_t)NB * Tc_cap * GD) * 4 > ws_size) Tc_cap >>= 1;
    float* xg      = ws + 2 * (size_t)NB * 256 * HD;      // NB*Tc_cap*GD floats
    float* cws     = xg + (size_t)NB * Tc_cap * GD;       // NB*HD floats
    unsigned* flags = (unsigned*)(cws + (size_t)NB * HD); // 256 u32

    auto layer = [&](const float* in, float* out, int T, int tier, int l) {
        const float* WihL = Wih[tier] + (size_t)l * GD * HD;
        const float* WhhL = Whh[tier] + (size_t)l * GD * HD;
        const float* bihL = bih[tier] + (size_t)l * GD;
        const float* bhhL = bhh[tier] + (size_t)l * GD;
        const float* h0L  = h0[tier] + (size_t)l * NB * HD;
        hipMemcpyAsync(cws, c0[tier] + (size_t)l * NB * HD, (size_t)NB * HD * sizeof(float),
                       hipMemcpyDeviceToDevice, stream);
        const int Tc = T < Tc_cap ? T : Tc_cap;
        int tc_bits = 0; while ((1 << tc_bits) < Tc) ++tc_bits;
        for (int t0 = 0; t0 < T; t0 += Tc) {
            dim3 g((NB * Tc) / 64, GD / 64);
            gemm_xg<<<g, 256, 0, stream>>>(in, T, t0, tc_bits, WihL, bihL, bhhL, xg);
            hipMemsetAsync(flags, 0, 256 * sizeof(unsigned), stream);
            const float* xg_p = xg; int Tc_a = Tc;
            const float* Whh_p = WhhL; const float* h0_p = h0L;
            float* out_p = out; int T_a = T; int t0_a = t0;
            float* cws_p = cws; unsigned* flags_p = flags;
            void* args[] = {(void*)&xg_p, (void*)&Tc_a, (void*)&Whh_p, (void*)&h0_p,
                            (void*)&out_p, (void*)&T_a, (void*)&t0_a,
                            (void*)&cws_p, (void*)&flags_p};
            hipLaunchCooperativeKernel((const void*)lstm_scan, dim3(256), dim3(256),
                                       args, 0, stream);
        }
    };

    float* dout = (float*)d_out;

    // Tier 0 (T=128)
    layer(x[0], bufA, 128, 0, 0);
    layer(bufA, bufB, 128, 0, 1);
    {
        dim3 g((NB * 128) / 64, 1024 / 64);
        gemm_up<<<g, 256, 0, stream>>>(bufB, upW[0], 1024, upb[0], x[1], bufA, 7, 1);
    }
    // Tier 1 (T=256)
    layer(bufA, bufB, 256, 1, 0);
    layer(bufB, bufA, 256, 1, 1);
    {
        dim3 g((NB * 256) / 64, 4096 / 64);
        gemm_up<<<g, 256, 0, stream>>>(bufA, upW[1], 4096, upb[1], x[2], dout, 8, 3);
    }
    // Tier 2 (T=2048), chunked in-place on d_out
    layer(dout, dout, 2048, 2, 0);
    layer(dout, dout, 2048, 2, 1);
}

// Round 3
// 48591.476 us; speedup vs baseline: 3.9301x; 3.9301x over previous
//
#include <hip/hip_runtime.h>
#include <cstddef>
#include <cstdint>

#define NB 32     // batch
#define HD 512    // hidden
#define GD 2048   // 4*hidden

typedef __attribute__((ext_vector_type(8))) short bf16x8;
typedef __attribute__((ext_vector_type(8))) unsigned short u16x8;
typedef __attribute__((ext_vector_type(4))) float f32x4;

__device__ __forceinline__ float sigf(float x)   { return 1.0f / (1.0f + __expf(-x)); }
__device__ __forceinline__ float tanhf_(float x) { return 2.0f / (1.0f + __expf(-2.0f * x)) - 1.0f; }

__device__ __forceinline__ unsigned short f2bf(float x) {
    unsigned u = __float_as_uint(x);
    return (unsigned short)((u + 0x7fffu + ((u >> 16) & 1u)) >> 16);
}
__device__ __forceinline__ float bf2f(unsigned short h) {
    return __uint_as_float(((unsigned)h) << 16);
}

// split 8 fp32 into hi/lo bf16 vectors
__device__ __forceinline__ void split8(const float4 a, const float4 b, u16x8& hi, u16x8& lo) {
    float v[8] = {a.x, a.y, a.z, a.w, b.x, b.y, b.z, b.w};
#pragma unroll
    for (int q = 0; q < 8; ++q) {
        const unsigned short h = f2bf(v[q]);
        hi[q] = h;
        lo[q] = f2bf(v[q] - bf2f(h));
    }
}

__global__ __launch_bounds__(256) void split_kernel(
    const float* __restrict__ src, unsigned short* __restrict__ hi,
    unsigned short* __restrict__ lo, int n)
{
    const int i = blockIdx.x * 256 + threadIdx.x;
    if (i < n) {
        const float x = src[i];
        const unsigned short h = f2bf(x);
        hi[i] = h;
        lo[i] = f2bf(x - bf2f(h));
    }
}

// Split-bf16 MFMA GEMM, C tile 64x64, K=512.
// MODE 0 (xg): A rows = chunked (b, t0+tc) of (B,T,HD); B = W (GD,HD) row-major (NT);
//              out[mg*2048+n] = acc + b1[n] + b2x[n]
// MODE 1 (up): A rows = m directly of (B*T, HD); B = W (HD, N) row-major (NN);
//              scatter-unfold epilogue + bias + xnext add
template<int MODE>
__global__ __launch_bounds__(256) void mfma_gemm(
    const float* __restrict__ A, int T, int t0, int tc_bits,
    const float* __restrict__ W, int N,
    const float* __restrict__ b1, const float* __restrict__ b2x,
    float* __restrict__ out, int t_bits, int u_bits)
{
    __shared__ __align__(16) unsigned short Ah[64][40], Al[64][40], Bh[64][40], Bl[64][40];
    const int tid = threadIdx.x;
    const int m0 = blockIdx.x << 6, n0 = blockIdx.y << 6;

    const int ar = tid >> 2, aks = (tid & 3) << 3;
    const float* aPtr;
    if (MODE == 0) {
        const int rg = m0 + ar;
        const int b = rg >> tc_bits;
        const int tt = t0 + (rg & ((1 << tc_bits) - 1));
        aPtr = A + (((size_t)b * T + tt) << 9) + aks;
    } else {
        aPtr = A + (((size_t)(m0 + ar)) << 9) + aks;
    }
    const float* bPtr = nullptr;
    int bkk = 0, bns = 0;
    if (MODE == 0) {
        bPtr = W + (((size_t)(n0 + ar)) << 9) + aks;
    } else {
        bkk = tid >> 3; bns = (tid & 7) << 3;
        bPtr = W + (size_t)bkk * N + n0 + bns;
    }

    const int lane = tid & 63, wv = tid >> 6;
    const int fr = lane & 15, ko = (lane >> 4) << 3;
    f32x4 acc[4] = {};

    for (int k0 = 0; k0 < HD; k0 += 32) {
        // stage A (64 rows x 32 k) as split bf16
        {
            const float4 a1 = *(const float4*)(aPtr + k0);
            const float4 a2 = *(const float4*)(aPtr + k0 + 4);
            u16x8 vh, vl; split8(a1, a2, vh, vl);
            *(u16x8*)&Ah[ar][aks] = vh;
            *(u16x8*)&Al[ar][aks] = vl;
        }
        if (MODE == 0) {
            const float4 w1 = *(const float4*)(bPtr + k0);
            const float4 w2 = *(const float4*)(bPtr + k0 + 4);
            u16x8 vh, vl; split8(w1, w2, vh, vl);
            *(u16x8*)&Bh[ar][aks] = vh;
            *(u16x8*)&Bl[ar][aks] = vl;
        } else {
            const float4 w1 = *(const float4*)(bPtr + (size_t)k0 * N);
            const float4 w2 = *(const float4*)(bPtr + (size_t)k0 * N + 4);
            u16x8 vh, vl; split8(w1, w2, vh, vl);
#pragma unroll
            for (int q = 0; q < 8; ++q) {
                Bh[bns + q][bkk] = vh[q];
                Bl[bns + q][bkk] = vl[q];
            }
        }
        __syncthreads();
        const bf16x8 ahf = *(const bf16x8*)&Ah[(wv << 4) + fr][ko];
        const bf16x8 alf = *(const bf16x8*)&Al[(wv << 4) + fr][ko];
#pragma unroll
        for (int nt = 0; nt < 4; ++nt) {
            const bf16x8 bhf = *(const bf16x8*)&Bh[(nt << 4) + fr][ko];
            const bf16x8 blf = *(const bf16x8*)&Bl[(nt << 4) + fr][ko];
            acc[nt] = __builtin_amdgcn_mfma_f32_16x16x32_bf16(ahf, bhf, acc[nt], 0, 0, 0);
            acc[nt] = __builtin_amdgcn_mfma_f32_16x16x32_bf16(ahf, blf, acc[nt], 0, 0, 0);
            acc[nt] = __builtin_amdgcn_mfma_f32_16x16x32_bf16(alf, bhf, acc[nt], 0, 0, 0);
        }
        __syncthreads();
    }

    // C layout: row m = wv*16 + (lane>>4)*4 + r ; col n = nt*16 + (lane&15)
    const int mlb = (wv << 4) + ((lane >> 4) << 2);
#pragma unroll
    for (int r = 0; r < 4; ++r) {
        const int mg = m0 + mlb + r;
#pragma unroll
        for (int nt = 0; nt < 4; ++nt) {
            const int n = n0 + (nt << 4) + fr;
            const float v = acc[nt][r];
            if (MODE == 0) {
                out[((size_t)mg << 11) + n] = v + b1[n] + b2x[n];
            } else {
                const int bb = mg >> t_bits, tt = mg & ((1 << t_bits) - 1);
                const int uu = n >> 9, hh = n & 511;
                const size_t di = (((size_t)((((bb << t_bits) + tt) << u_bits) + uu)) << 9) + hh;
                out[di] = v + b1[n] + b2x[di];
            }
        }
    }
}

// One recurrence step via split-bf16 MFMA.
// 128 blocks x 64 threads. Block owns 4 hidden units j0..j0+3, all 4 gates
// (16 gate rows, row_map(i) = (i>>2)*512 + j0 + (i&3)), batch 32 = 2 C tiles.
__global__ __launch_bounds__(64) void lstm_step_mfma(
    const float* __restrict__ xg, int Tc, int s,
    const unsigned short* __restrict__ whh_hi, const unsigned short* __restrict__ whh_lo,
    const unsigned short* __restrict__ hh_in, const unsigned short* __restrict__ hl_in,
    unsigned short* __restrict__ hh_out, unsigned short* __restrict__ hl_out,
    float* __restrict__ cws, float* __restrict__ outh, int T, int t)
{
    __shared__ float gl[16][33];
    const int lane = threadIdx.x;
    const int j0 = blockIdx.x << 2;
    const int fr = lane & 15;
    const int ko = (lane >> 4) << 3;
    const int g = lane >> 4;

    const int arow = ((fr >> 2) << 9) + j0 + (fr & 3);
    const unsigned short* pAh = whh_hi + ((size_t)arow << 9) + ko;
    const unsigned short* pAl = whh_lo + ((size_t)arow << 9) + ko;
    const unsigned short* pB0h = hh_in + (fr << 9) + ko;
    const unsigned short* pB0l = hl_in + (fr << 9) + ko;
    const unsigned short* pB1h = hh_in + ((fr + 16) << 9) + ko;
    const unsigned short* pB1l = hl_in + ((fr + 16) << 9) + ko;

    // init accumulators with xg (bih+bhh already folded in)
    f32x4 acc0 = *(const f32x4*)(xg + (((size_t)fr * Tc + s) << 11) + (g << 9) + j0);
    f32x4 acc1 = *(const f32x4*)(xg + (((size_t)(fr + 16) * Tc + s) << 11) + (g << 9) + j0);

#pragma unroll 4
    for (int ck = 0; ck < 16; ++ck) {
        const int o = ck << 5;
        const bf16x8 ah  = *(const bf16x8*)(pAh + o);
        const bf16x8 al  = *(const bf16x8*)(pAl + o);
        const bf16x8 b0h = *(const bf16x8*)(pB0h + o);
        const bf16x8 b0l = *(const bf16x8*)(pB0l + o);
        const bf16x8 b1h = *(const bf16x8*)(pB1h + o);
        const bf16x8 b1l = *(const bf16x8*)(pB1l + o);
        acc0 = __builtin_amdgcn_mfma_f32_16x16x32_bf16(ah, b0h, acc0, 0, 0, 0);
        acc0 = __builtin_amdgcn_mfma_f32_16x16x32_bf16(ah, b0l, acc0, 0, 0, 0);
        acc0 = __builtin_amdgcn_mfma_f32_16x16x32_bf16(al, b0h, acc0, 0, 0, 0);
        acc1 = __builtin_amdgcn_mfma_f32_16x16x32_bf16(ah, b1h, acc1, 0, 0, 0);
        acc1 = __builtin_amdgcn_mfma_f32_16x16x32_bf16(ah, b1l, acc1, 0, 0, 0);
        acc1 = __builtin_amdgcn_mfma_f32_16x16x32_bf16(al, b1h, acc1, 0, 0, 0);
    }

    // C layout: row m = g*4 + r (gate g, hidden j0+r), col = batch
#pragma unroll
    for (int r = 0; r < 4; ++r) {
        gl[(g << 2) + r][fr] = acc0[r];
        gl[(g << 2) + r][16 + fr] = acc1[r];
    }
    __syncthreads();
#pragma unroll
    for (int p = 0; p < 2; ++p) {
        const int o = lane + (p << 6);
        const int b = o & 31, jr = o >> 5;
        const float gi = gl[jr][b], gf = gl[4 + jr][b];
        const float gg = gl[8 + jr][b], go = gl[12 + jr][b];
        const size_t ci = ((size_t)b << 9) + j0 + jr;
        const float c = sigf(gf) * cws[ci] + sigf(gi) * tanhf_(gg);
        cws[ci] = c;
        const float h = sigf(go) * tanhf_(c);
        outh[(((size_t)b * T + t) << 9) + j0 + jr] = h;
        const unsigned short hb = f2bf(h);
        hh_out[ci] = hb;
        hl_out[ci] = f2bf(h - bf2f(hb));
    }
}

extern "C" void kernel_launch(void* const* d_in, const int* in_sizes, int n_in,
                              void* d_out, int out_size, void* d_ws, size_t ws_size,
                              hipStream_t stream)
{
    const float* x[3]   = {(const float*)d_in[0], (const float*)d_in[1],  (const float*)d_in[2]};
    const float* Wih[3] = {(const float*)d_in[3], (const float*)d_in[9],  (const float*)d_in[15]};
    const float* Whh[3] = {(const float*)d_in[4], (const float*)d_in[10], (const float*)d_in[16]};
    const float* bih[3] = {(const float*)d_in[5], (const float*)d_in[11], (const float*)d_in[17]};
    const float* bhh[3] = {(const float*)d_in[6], (const float*)d_in[12], (const float*)d_in[18]};
    const float* h0[3]  = {(const float*)d_in[7], (const float*)d_in[13], (const float*)d_in[19]};
    const float* c0[3]  = {(const float*)d_in[8], (const float*)d_in[14], (const float*)d_in[20]};
    const float* upW[2] = {(const float*)d_in[21], (const float*)d_in[23]};
    const float* upb[2] = {(const float*)d_in[22], (const float*)d_in[24]};

    float* ws = (float*)d_ws;
    float* bufA = ws;                                   // NB*256*HD = 4,194,304 f
    float* bufB = bufA + (size_t)NB * 256 * HD;
    float* cws  = bufB + (size_t)NB * 256 * HD;         // NB*HD
    float* xg   = cws + (size_t)NB * HD;                // NB*Tc_cap*GD

    // fixed tail: whh hi/lo (2 x 1,048,576 u16) + hbuf (4 x 16,384 u16)
    const size_t tail_f = (2 * (size_t)GD * HD + 4 * (size_t)NB * HD) / 2;
    const size_t fixed_f = 2 * (size_t)NB * 256 * HD + (size_t)NB * HD + tail_f;
    int Tc_cap = 256;
    while (Tc_cap > 32 && (fixed_f + (size_t)NB * Tc_cap * GD) * 4 > ws_size) Tc_cap >>= 1;

    unsigned short* whh_hi = (unsigned short*)(xg + (size_t)NB * Tc_cap * GD);
    unsigned short* whh_lo = whh_hi + (size_t)GD * HD;
    unsigned short* hbH[2], * hbL[2];
    hbH[0] = whh_lo + (size_t)GD * HD;
    hbL[0] = hbH[0] + (size_t)NB * HD;
    hbH[1] = hbL[0] + (size_t)NB * HD;
    hbL[1] = hbH[1] + (size_t)NB * HD;

    auto layer = [&](const float* in, float* out, int T, int tier, int l) {
        const float* WihL = Wih[tier] + (size_t)l * GD * HD;
        const float* WhhL = Whh[tier] + (size_t)l * GD * HD;
        const float* bihL = bih[tier] + (size_t)l * GD;
        const float* bhhL = bhh[tier] + (size_t)l * GD;
        const float* h0L  = h0[tier] + (size_t)l * NB * HD;

        split_kernel<<<(GD * HD + 255) / 256, 256, 0, stream>>>(WhhL, whh_hi, whh_lo, GD * HD);
        split_kernel<<<(NB * HD + 255) / 256, 256, 0, stream>>>(h0L, hbH[0], hbL[0], NB * HD);
        hipMemcpyAsync(cws, c0[tier] + (size_t)l * NB * HD, (size_t)NB * HD * sizeof(float),
                       hipMemcpyDeviceToDevice, stream);

        const int Tc = T < Tc_cap ? T : Tc_cap;
        int tc_bits = 0; while ((1 << tc_bits) < Tc) ++tc_bits;
        for (int t0 = 0; t0 < T; t0 += Tc) {
            dim3 g((NB * Tc) / 64, GD / 64);
            mfma_gemm<0><<<g, 256, 0, stream>>>(in, T, t0, tc_bits, WihL, GD,
                                                bihL, bhhL, xg, 0, 0);
            for (int s = 0; s < Tc; ++s) {
                const int t = t0 + s;
                lstm_step_mfma<<<128, 64, 0, stream>>>(
                    xg, Tc, s, whh_hi, whh_lo,
                    hbH[t & 1], hbL[t & 1], hbH[(t + 1) & 1], hbL[(t + 1) & 1],
                    cws, out, T, t);
            }
        }
    };

    float* dout = (float*)d_out;

    // Tier 0 (T=128)
    layer(x[0], bufA, 128, 0, 0);
    layer(bufA, bufB, 128, 0, 1);
    {   // upsample 0: (B,128,512) -> (B,256,512) + x1 -> bufA
        dim3 g((NB * 128) / 64, 1024 / 64);
        mfma_gemm<1><<<g, 256, 0, stream>>>(bufB, 0, 0, 0, upW[0], 1024,
                                            upb[0], x[1], bufA, 7, 1);
    }
    // Tier 1 (T=256)
    layer(bufA, bufB, 256, 1, 0);
    layer(bufB, bufA, 256, 1, 1);
    {   // upsample 1: (B,256,512) -> (B,2048,512) + x2 -> d_out
        dim3 g((NB * 256) / 64, 4096 / 64);
        mfma_gemm<1><<<g, 256, 0, stream>>>(bufA, 0, 0, 0, upW[1], 4096,
                                            upb[1], x[2], dout, 8, 3);
    }
    // Tier 2 (T=2048), chunked in-place on d_out
    layer(dout, dout, 2048, 2, 0);
    layer(dout, dout, 2048, 2, 1);
}

// Round 4
// 22307.896 us; speedup vs baseline: 8.5606x; 2.1782x over previous
//
#include <hip/hip_runtime.h>
#include <cstddef>
#include <cstdint>

#define NB 32     // batch
#define HD 512    // hidden
#define GD 2048   // 4*hidden

typedef unsigned short u16;
typedef __attribute__((ext_vector_type(8))) short bf16x8;
typedef __attribute__((ext_vector_type(8))) unsigned short u16x8;
typedef __attribute__((ext_vector_type(4))) float f32x4;

#define MFMA16(a, b, c) __builtin_amdgcn_mfma_f32_16x16x32_bf16((a), (b), (c), 0, 0, 0)

__device__ __forceinline__ float sigf(float x)   { return 1.0f / (1.0f + __expf(-x)); }
__device__ __forceinline__ float tanhf_(float x) { return 2.0f / (1.0f + __expf(-2.0f * x)) - 1.0f; }

__device__ __forceinline__ u16 f2bf(float x) {
    unsigned u = __float_as_uint(x);
    return (u16)((u + 0x7fffu + ((u >> 16) & 1u)) >> 16);
}
__device__ __forceinline__ float bf2f(u16 h) {
    return __uint_as_float(((unsigned)h) << 16);
}

__device__ __forceinline__ void split8(const float4 a, const float4 b, u16x8& hi, u16x8& lo) {
    float v[8] = {a.x, a.y, a.z, a.w, b.x, b.y, b.z, b.w};
#pragma unroll
    for (int q = 0; q < 8; ++q) {
        const u16 h = f2bf(v[q]);
        hi[q] = h;
        lo[q] = f2bf(v[q] - bf2f(h));
    }
}

__global__ __launch_bounds__(256) void split_kernel(
    const float* __restrict__ src, u16* __restrict__ hi, u16* __restrict__ lo, int n)
{
    const int i = blockIdx.x * 256 + threadIdx.x;
    if (i < n) {
        const float x = src[i];
        const u16 h = f2bf(x);
        hi[i] = h;
        lo[i] = f2bf(x - bf2f(h));
    }
}

__global__ __launch_bounds__(256) void addv_kernel(
    const float* __restrict__ a, const float* __restrict__ b, float* __restrict__ o, int n)
{
    const int i = blockIdx.x * 256 + threadIdx.x;
    if (i < n) o[i] = a[i] + b[i];
}

// Split-bf16 MFMA GEMM, C tile 64x64, K=512.
// MODE 0 (xg): A rows = chunked (b-major) of (B,T,HD); B = W (GD,HD) row-major (NT);
// MODE 1 (up): A rows = m of (B*T, HD); B = W (HD,N) (NN); scatter-unfold epilogue.
template<int MODE>
__global__ __launch_bounds__(256) void mfma_gemm(
    const float* __restrict__ A, int T, int t0, int tc_bits,
    const float* __restrict__ W, int N,
    const float* __restrict__ b1, const float* __restrict__ b2x,
    float* __restrict__ out, int t_bits, int u_bits)
{
    __shared__ __align__(16) u16 Ah[64][40], Al[64][40], Bh[64][40], Bl[64][40];
    const int tid = threadIdx.x;
    const int m0 = blockIdx.x << 6, n0 = blockIdx.y << 6;

    const int ar = tid >> 2, aks = (tid & 3) << 3;
    const float* aPtr;
    if (MODE == 0) {
        const int rg = m0 + ar;
        const int b = rg >> tc_bits;
        const int tt = t0 + (rg & ((1 << tc_bits) - 1));
        aPtr = A + (((size_t)b * T + tt) << 9) + aks;
    } else {
        aPtr = A + (((size_t)(m0 + ar)) << 9) + aks;
    }
    const float* bPtr = nullptr;
    int bkk = 0, bns = 0;
    if (MODE == 0) {
        bPtr = W + (((size_t)(n0 + ar)) << 9) + aks;
    } else {
        bkk = tid >> 3; bns = (tid & 7) << 3;
        bPtr = W + (size_t)bkk * N + n0 + bns;
    }

    const int lane = tid & 63, wv = tid >> 6;
    const int fr = lane & 15, ko = (lane >> 4) << 3;
    f32x4 acc[4] = {};

    for (int k0 = 0; k0 < HD; k0 += 32) {
        {
            const float4 a1 = *(const float4*)(aPtr + k0);
            const float4 a2 = *(const float4*)(aPtr + k0 + 4);
            u16x8 vh, vl; split8(a1, a2, vh, vl);
            *(u16x8*)&Ah[ar][aks] = vh;
            *(u16x8*)&Al[ar][aks] = vl;
        }
        if (MODE == 0) {
            const float4 w1 = *(const float4*)(bPtr + k0);
            const float4 w2 = *(const float4*)(bPtr + k0 + 4);
            u16x8 vh, vl; split8(w1, w2, vh, vl);
            *(u16x8*)&Bh[ar][aks] = vh;
            *(u16x8*)&Bl[ar][aks] = vl;
        } else {
            const float4 w1 = *(const float4*)(bPtr + (size_t)k0 * N);
            const float4 w2 = *(const float4*)(bPtr + (size_t)k0 * N + 4);
            u16x8 vh, vl; split8(w1, w2, vh, vl);
#pragma unroll
            for (int q = 0; q < 8; ++q) {
                Bh[bns + q][bkk] = vh[q];
                Bl[bns + q][bkk] = vl[q];
            }
        }
        __syncthreads();
        const bf16x8 ahf = *(const bf16x8*)&Ah[(wv << 4) + fr][ko];
        const bf16x8 alf = *(const bf16x8*)&Al[(wv << 4) + fr][ko];
#pragma unroll
        for (int nt = 0; nt < 4; ++nt) {
            const bf16x8 bhf = *(const bf16x8*)&Bh[(nt << 4) + fr][ko];
            const bf16x8 blf = *(const bf16x8*)&Bl[(nt << 4) + fr][ko];
            acc[nt] = MFMA16(ahf, bhf, acc[nt]);
            acc[nt] = MFMA16(ahf, blf, acc[nt]);
            acc[nt] = MFMA16(alf, bhf, acc[nt]);
        }
        __syncthreads();
    }

    const int mlb = (wv << 4) + ((lane >> 4) << 2);
#pragma unroll
    for (int r = 0; r < 4; ++r) {
        const int mg = m0 + mlb + r;
#pragma unroll
        for (int nt = 0; nt < 4; ++nt) {
            const int n = n0 + (nt << 4) + fr;
            const float v = acc[nt][r];
            if (MODE == 0) {
                out[((size_t)mg << 11) + n] = v + b1[n] + b2x[n];
            } else {
                const int bb = mg >> t_bits, tt = mg & ((1 << t_bits) - 1);
                const int uu = n >> 9, hh = n & 511;
                const size_t di = (((size_t)((((bb << t_bits) + tt) << u_bits) + uu)) << 9) + hh;
                out[di] = v + b1[n] + b2x[di];
            }
        }
    }
}

// Fused diagonal 2-layer LSTM step. Launch j (0..T):
//   blocks [0,64):   layer0 step t=j   (skip if j==T): 8 hidden units, K=512
//   blocks [64,192): layer1 step t=j-1 (skip if j==0): 4 hidden units, K=1024
// 256 threads = 4 waves, K split across waves, LDS partial reduction.
// Rings: [slot(2)][hi/lo][batch(32)][512] u16; slot stride 32768, hl stride 16384.
__global__ __launch_bounds__(256) void lstm_step2(
    const float* __restrict__ xg, int Tc, int s,
    const u16* __restrict__ w0h, const u16* __restrict__ w0l,
    const u16* __restrict__ w1ih_h, const u16* __restrict__ w1ih_l,
    const u16* __restrict__ w1hh_h, const u16* __restrict__ w1hh_l,
    const float* __restrict__ bsum1,
    u16* __restrict__ ring0, u16* __restrict__ ring1,
    float* __restrict__ c0ws, float* __restrict__ c1ws,
    float* __restrict__ out1, int T, int j)
{
    __shared__ float red[4][32][33];
    const int tid = threadIdx.x;
    const int wv = tid >> 6, lane = tid & 63;
    const int fr = lane & 15;          // A: local gate-row; B: batch within ntile
    const int ko8 = (lane >> 4) << 3;  // 8-elem k granule
    const int g = lane >> 4;           // gate index for C rows / init

    if ((int)blockIdx.x < 64) {
        // ---------------- layer 0 ----------------
        if (j >= T) return;
        const int t = j;
        const int j0 = (int)blockIdx.x << 3;          // 8 hidden units
        const u16* rin_h = ring0 + (((t - 1) & 1) * 32768);
        const u16* rin_l = rin_h + 16384;
        const int kb = wv << 7;                        // wave K-base (128)
        const int arow0 = ((fr >> 2) << 9) + j0 + (fr & 3);
        const int arow1 = arow0 + 4;
        f32x4 acc[2][2] = {};
        if (wv == 0) {
#pragma unroll
            for (int nt = 0; nt < 2; ++nt) {
                const int b = (nt << 4) + fr;
                const float* xp = xg + (((size_t)b * Tc + s) << 11) + (g << 9) + j0;
                acc[0][nt] = *(const f32x4*)(xp);
                acc[1][nt] = *(const f32x4*)(xp + 4);
            }
        }
#pragma unroll
        for (int ck = 0; ck < 4; ++ck) {
            const int k = kb + (ck << 5) + ko8;
            const bf16x8 a0h = *(const bf16x8*)(w0h + (((size_t)arow0) << 9) + k);
            const bf16x8 a0l = *(const bf16x8*)(w0l + (((size_t)arow0) << 9) + k);
            const bf16x8 a1h = *(const bf16x8*)(w0h + (((size_t)arow1) << 9) + k);
            const bf16x8 a1l = *(const bf16x8*)(w0l + (((size_t)arow1) << 9) + k);
#pragma unroll
            for (int nt = 0; nt < 2; ++nt) {
                const int br = (nt << 4) + fr;
                const bf16x8 bh = *(const bf16x8*)(rin_h + (br << 9) + k);
                const bf16x8 bl = *(const bf16x8*)(rin_l + (br << 9) + k);
                acc[0][nt] = MFMA16(a0h, bh, acc[0][nt]);
                acc[0][nt] = MFMA16(a0h, bl, acc[0][nt]);
                acc[0][nt] = MFMA16(a0l, bh, acc[0][nt]);
                acc[1][nt] = MFMA16(a1h, bh, acc[1][nt]);
                acc[1][nt] = MFMA16(a1h, bl, acc[1][nt]);
                acc[1][nt] = MFMA16(a1l, bh, acc[1][nt]);
            }
        }
#pragma unroll
        for (int mt = 0; mt < 2; ++mt)
#pragma unroll
            for (int nt = 0; nt < 2; ++nt)
#pragma unroll
                for (int r = 0; r < 4; ++r)
                    red[wv][(mt << 4) + (g << 2) + r][(nt << 4) + fr] = acc[mt][nt][r];
        __syncthreads();
        // epilogue: thread -> (hidden jr 0..7, batch b 0..31)
        const int jr = tid >> 5, b = tid & 31;
        const int mrow = ((jr >> 2) << 4) + (jr & 3);
        float gv[4];
#pragma unroll
        for (int gg = 0; gg < 4; ++gg) {
            const int rr = mrow + (gg << 2);
            gv[gg] = red[0][rr][b] + red[1][rr][b] + red[2][rr][b] + red[3][rr][b];
        }
        const int hidden = j0 + jr;
        const size_t ci = ((size_t)b << 9) + hidden;
        const float c = sigf(gv[1]) * c0ws[ci] + sigf(gv[0]) * tanhf_(gv[2]);
        c0ws[ci] = c;
        const float h = sigf(gv[3]) * tanhf_(c);
        u16* wr = ring0 + ((t & 1) * 32768);
        const u16 hb = f2bf(h);
        wr[ci] = hb;
        wr[16384 + ci] = f2bf(h - bf2f(hb));
    } else {
        // ---------------- layer 1 ----------------
        if (j == 0) return;
        const int t = j - 1;
        const int j0 = ((int)blockIdx.x - 64) << 2;    // 4 hidden units
        const int arow = ((fr >> 2) << 9) + j0 + (fr & 3);
        const u16 *Ah, *Al, *Bh, *Bl;
        const int kloc = (wv & 1) << 8;                // 0 or 256 within the 512-matrix
        if (wv < 2) {
            Ah = w1ih_h; Al = w1ih_l;
            Bh = ring0 + ((t & 1) * 32768); Bl = Bh + 16384;       // x_t = h0_t
        } else {
            Ah = w1hh_h; Al = w1hh_l;
            Bh = ring1 + (((t - 1) & 1) * 32768); Bl = Bh + 16384; // h1_{t-1}
        }
        f32x4 acc[2] = {};
        if (wv == 0) {
            const f32x4 bv = *(const f32x4*)(bsum1 + (g << 9) + j0);
            acc[0] = bv; acc[1] = bv;
        }
#pragma unroll
        for (int ck = 0; ck < 8; ++ck) {
            const int k = kloc + (ck << 5) + ko8;
            const bf16x8 ah = *(const bf16x8*)(Ah + (((size_t)arow) << 9) + k);
            const bf16x8 al = *(const bf16x8*)(Al + (((size_t)arow) << 9) + k);
#pragma unroll
            for (int nt = 0; nt < 2; ++nt) {
                const int br = (nt << 4) + fr;
                const bf16x8 bh = *(const bf16x8*)(Bh + (br << 9) + k);
                const bf16x8 bl = *(const bf16x8*)(Bl + (br << 9) + k);
                acc[nt] = MFMA16(ah, bh, acc[nt]);
                acc[nt] = MFMA16(ah, bl, acc[nt]);
                acc[nt] = MFMA16(al, bh, acc[nt]);
            }
        }
#pragma unroll
        for (int nt = 0; nt < 2; ++nt)
#pragma unroll
            for (int r = 0; r < 4; ++r)
                red[wv][(g << 2) + r][(nt << 4) + fr] = acc[nt][r];
        __syncthreads();
        if (tid < 128) {
            const int jr = tid >> 5, b = tid & 31;     // jr 0..3
            float gv[4];
#pragma unroll
            for (int gg = 0; gg < 4; ++gg) {
                const int rr = (gg << 2) + jr;
                gv[gg] = red[0][rr][b] + red[1][rr][b] + red[2][rr][b] + red[3][rr][b];
            }
            const int hidden = j0 + jr;
            const size_t ci = ((size_t)b << 9) + hidden;
            const float c = sigf(gv[1]) * c1ws[ci] + sigf(gv[0]) * tanhf_(gv[2]);
            c1ws[ci] = c;
            const float h = sigf(gv[3]) * tanhf_(c);
            u16* wr = ring1 + ((t & 1) * 32768);
            const u16 hb = f2bf(h);
            wr[ci] = hb;
            wr[16384 + ci] = f2bf(h - bf2f(hb));
            out1[(((size_t)b * T + t) << 9) + hidden] = h;
        }
    }
}

extern "C" void kernel_launch(void* const* d_in, const int* in_sizes, int n_in,
                              void* d_out, int out_size, void* d_ws, size_t ws_size,
                              hipStream_t stream)
{
    const float* x[3]   = {(const float*)d_in[0], (const float*)d_in[1],  (const float*)d_in[2]};
    const float* Wih[3] = {(const float*)d_in[3], (const float*)d_in[9],  (const float*)d_in[15]};
    const float* Whh[3] = {(const float*)d_in[4], (const float*)d_in[10], (const float*)d_in[16]};
    const float* bih[3] = {(const float*)d_in[5], (const float*)d_in[11], (const float*)d_in[17]};
    const float* bhh[3] = {(const float*)d_in[6], (const float*)d_in[12], (const float*)d_in[18]};
    const float* h0[3]  = {(const float*)d_in[7], (const float*)d_in[13], (const float*)d_in[19]};
    const float* c0[3]  = {(const float*)d_in[8], (const float*)d_in[14], (const float*)d_in[20]};
    const float* upW[2] = {(const float*)d_in[21], (const float*)d_in[23]};
    const float* upb[2] = {(const float*)d_in[22], (const float*)d_in[24]};

    float* ws = (float*)d_ws;
    float* bufA  = ws;                         // NB*256*HD
    float* bufB  = bufA + (size_t)NB * 256 * HD;
    float* c0ws  = bufB + (size_t)NB * 256 * HD;
    float* c1ws  = c0ws + (size_t)NB * HD;
    float* bsum1 = c1ws + (size_t)NB * HD;
    float* xg    = bsum1 + GD;

    const size_t head_f = 2 * (size_t)NB * 256 * HD + 2 * (size_t)NB * HD + GD;
    const size_t tail_u16 = 6 * (size_t)GD * HD + 2 * 65536;
    const size_t tail_f = (tail_u16 + 1) / 2;
    int Tc_cap = 256;
    while (Tc_cap > 32 && (head_f + (size_t)NB * Tc_cap * GD + tail_f) * 4 > ws_size)
        Tc_cap >>= 1;

    u16* w0h    = (u16*)(xg + (size_t)NB * Tc_cap * GD);
    u16* w0l    = w0h + (size_t)GD * HD;
    u16* w1ih_h = w0l + (size_t)GD * HD;
    u16* w1ih_l = w1ih_h + (size_t)GD * HD;
    u16* w1hh_h = w1ih_l + (size_t)GD * HD;
    u16* w1hh_l = w1hh_h + (size_t)GD * HD;
    u16* ring0  = w1hh_l + (size_t)GD * HD;    // 2*2*NB*HD u16
    u16* ring1  = ring0 + 4 * (size_t)NB * HD;

    auto tier = [&](const float* in, float* out1, int T, int tr) {
        const float* Wih0L = Wih[tr];
        const float* Whh0L = Whh[tr];
        const float* Wih1L = Wih[tr] + (size_t)GD * HD;
        const float* Whh1L = Whh[tr] + (size_t)GD * HD;

        split_kernel<<<(GD * HD) / 256, 256, 0, stream>>>(Whh0L, w0h, w0l, GD * HD);
        split_kernel<<<(GD * HD) / 256, 256, 0, stream>>>(Wih1L, w1ih_h, w1ih_l, GD * HD);
        split_kernel<<<(GD * HD) / 256, 256, 0, stream>>>(Whh1L, w1hh_h, w1hh_l, GD * HD);
        addv_kernel<<<GD / 256, 256, 0, stream>>>(bih[tr] + GD, bhh[tr] + GD, bsum1, GD);
        // h0 -> ring slot 1 (read at t=0 via (t-1)&1 == 1)
        split_kernel<<<(NB * HD) / 256, 256, 0, stream>>>(
            h0[tr], ring0 + 32768, ring0 + 32768 + 16384, NB * HD);
        split_kernel<<<(NB * HD) / 256, 256, 0, stream>>>(
            h0[tr] + (size_t)NB * HD, ring1 + 32768, ring1 + 32768 + 16384, NB * HD);
        hipMemcpyAsync(c0ws, c0[tr], (size_t)NB * HD * sizeof(float),
                       hipMemcpyDeviceToDevice, stream);
        hipMemcpyAsync(c1ws, c0[tr] + (size_t)NB * HD, (size_t)NB * HD * sizeof(float),
                       hipMemcpyDeviceToDevice, stream);

        const int Tc = T < Tc_cap ? T : Tc_cap;
        int tc_bits = 0; while ((1 << tc_bits) < Tc) ++tc_bits;
        for (int t0 = 0; t0 < T; t0 += Tc) {
            dim3 g((NB * Tc) / 64, GD / 64);
            mfma_gemm<0><<<g, 256, 0, stream>>>(in, T, t0, tc_bits, Wih0L, GD,
                                                bih[tr], bhh[tr], xg, 0, 0);
            for (int s = 0; s < Tc; ++s) {
                lstm_step2<<<192, 256, 0, stream>>>(
                    xg, Tc, s, w0h, w0l, w1ih_h, w1ih_l, w1hh_h, w1hh_l,
                    bsum1, ring0, ring1, c0ws, c1ws, out1, T, t0 + s);
            }
        }
        // tail: layer-1 finishes step T-1
        lstm_step2<<<192, 256, 0, stream>>>(
            xg, Tc, 0, w0h, w0l, w1ih_h, w1ih_l, w1hh_h, w1hh_l,
            bsum1, ring0, ring1, c0ws, c1ws, out1, T, T);
    };

    float* dout = (float*)d_out;

    // Tier 0 (T=128): l1 series -> bufB
    tier(x[0], bufB, 128, 0);
    {   // upsample 0: bufB (B,128,512) -> bufA (B,256,512) + x1
        dim3 g((NB * 128) / 64, 1024 / 64);
        mfma_gemm<1><<<g, 256, 0, stream>>>(bufB, 0, 0, 0, upW[0], 1024,
                                            upb[0], x[1], bufA, 7, 1);
    }
    // Tier 1 (T=256): input bufA, l1 series -> bufB
    tier(bufA, bufB, 256, 1);
    {   // upsample 1: bufB (B,256,512) -> dout (B,2048,512) + x2
        dim3 g((NB * 256) / 64, 4096 / 64);
        mfma_gemm<1><<<g, 256, 0, stream>>>(bufB, 0, 0, 0, upW[1], 4096,
                                            upb[1], x[2], dout, 8, 3);
    }
    // Tier 2 (T=2048): input dout (chunked reads stay ahead of l1 writes), l1 -> dout
    tier(dout, dout, 2048, 2);
}